// Round 1
// 84.993 us; speedup vs baseline: 1.0067x; 1.0067x over previous
//
#include <hip/hip_runtime.h>
#include <hip/hip_fp16.h>
#include <math.h>

// StripePolynomial2d, round 7: slim register footprint + forced occupancy.
// Theory: R6's batched Phase B (9x uint4 + 9x u32 + 9 addrs live) pushed VGPRs
// past 128 -> low occupancy / possible scratch spills; kernel ran ~37us vs a
// ~10-15us pipe roofline (VALU ~8us, LDS ~8.5us, HBM ~8us).
// Changes vs R6:
//  - fused per-s loop (seg/xl -> 2 LDS reads -> Horner immediately): peak live
//    set ~2 records instead of 9; numerics bit-identical (same op order).
//  - __launch_bounds__(256, 4): force <=128 VGPR -> 16 waves/CU.
//  - grid 1024 blocks x 8 tiles: single resident round (4 blocks/CU), table
//    build amortized 8x.
//  - prefetch next tile's x loads (and first tile's ahead of table build).

#define NREC 576              // 9 ec * 64 seg
#define NTILE 8192            // 8 imgs * 1024 tiles
#define NBLK 1024

__device__ __forceinline__ __half2 u2h2(unsigned int u) {
    __half2 h; __builtin_memcpy(&h, &u, 4); return h;
}
__device__ __forceinline__ unsigned int h22u(__half2 h) {
    unsigned int u; __builtin_memcpy(&u, &h, 4); return u;
}

__device__ __forceinline__ void coeff_compute(const float* __restrict__ Wt, int r,
                                              unsigned int rec[8]) {
    int ec  = r >> 6;
    int seg = r & 63;
    int e   = ec / 3;
    int c   = ec - e * 3;
    int nb  = 2 * seg;
    float c0[3], c1[3], c2[3];
    #pragma unroll
    for (int o = 0; o < 3; ++o) {
        float w0, w1, w2;
        if (e == 0) {
            const float* p0 = Wt + ((0 * 3 + o) * 3 + c) * 129 + nb;
            const float* p1 = Wt + ((1 * 3 + o) * 3 + c) * 129 + nb;
            w0 = p0[0] + p1[0]; w1 = p0[1] + p1[1]; w2 = p0[2] + p1[2];
        } else {
            const float* p = Wt + (((e + 1) * 3 + o) * 3 + c) * 129 + nb;
            w0 = p[0]; w1 = p[1]; w2 = p[2];
        }
        c0[o] = 0.25f  * w1;
        c1[o] = 0.125f * (w2 - w0);
        c2[o] = 0.125f * (w0 + w2) - 0.25f * w1;
    }
    rec[0] = h22u(__floats2half2_rn(c0[0], c0[1]));
    rec[1] = h22u(__floats2half2_rn(c1[0], c1[1]));
    rec[2] = h22u(__floats2half2_rn(c2[0], c2[1]));
    rec[3] = h22u(__floats2half2_rn(c0[2], c1[2]));
    rec[4] = h22u(__floats2half2_rn(c2[2], 0.0f));
    rec[5] = 0u; rec[6] = 0u; rec[7] = 0u;
}

__global__ __launch_bounds__(256, 4) void stripe_all(
    const float* __restrict__ x, const float* __restrict__ Wt,
    float* __restrict__ out)
{
    __shared__ uint4 lw4[NREC * 2];   // 18432 B
    const unsigned int* lw = (const unsigned int*)lw4;
    const int tid = threadIdx.x;

    // ---- prefetch first tile's x while the table is being built ----
    const int t0 = blockIdx.x;
    float pf[3];
    {
        const int b  = t0 >> 10;
        const int p  = ((t0 & 1023) << 8) + tid;
        const int xb = ((b * 3) << 18) + p;
        pf[0] = x[xb];
        pf[1] = x[xb + (1 << 18)];
        pf[2] = x[xb + (2 << 18)];
    }

    // ---- build coeff table once per block ----
    for (int r = tid; r < NREC; r += 256) {
        unsigned int rec[8];
        coeff_compute(Wt, r, rec);
        lw4[2 * r]     = make_uint4(rec[0], rec[1], rec[2], rec[3]);
        lw4[2 * r + 1] = make_uint4(rec[4], rec[5], rec[6], rec[7]);
    }
    __syncthreads();

    // q_e = pos_e/8 + 32, f32 from compile-time f64 constants.
    constexpr double RATIO = 512.0 / 513.0;
    constexpr double CX = 0x1.6a09e667f3bcdp-1;  // cos(f64 pi/4)
    constexpr double SY = 0x1.6a09e667f3bccp-1;  // sin(f64 pi/4), 1 ulp lower
    constexpr double S0 = RATIO * 64.0 / 511.0;
    constexpr double R2MAX = CX * 511.0 + SY * 511.0;
    constexpr double S2 = RATIO * 64.0 / R2MAX;
    constexpr double MN3 = -(SY * 511.0);
    constexpr double MX3 = CX * 511.0;
    constexpr double S3 = RATIO * 64.0 / (MX3 - MN3);

    for (int t = t0; t < NTILE; t += NBLK) {
        const int b = t >> 10;
        const int p = ((t & 1023) << 8) + tid;
        const int w = p >> 9;
        const int h = p & 511;

        // current tile's x (prefetched), then prefetch the next tile's
        float xv[3] = { pf[0], pf[1], pf[2] };
        const int tn_ = t + NBLK;
        if (tn_ < NTILE) {
            const int b2  = tn_ >> 10;
            const int p2  = ((tn_ & 1023) << 8) + tid;
            const int xb2 = ((b2 * 3) << 18) + p2;
            pf[0] = x[xb2];
            pf[1] = x[xb2 + (1 << 18)];
            pf[2] = x[xb2 + (2 << 18)];
        }

        const float wf = (float)w, hf = (float)h;
        float qe[3];
        qe[0] = wf * (float)S0;
        qe[1] = fmaf(hf, (float)(SY * S2), wf * (float)(CX * S2));
        qe[2] = fmaf(hf, (float)(-(SY * S3)),
                     fmaf(wf, (float)(CX * S3), (float)(-MN3 * S3)));

        // ---- fused per-s: seg/xl -> 2 LDS reads -> Horner, minimal live set ----
        float acc0 = 0.f, acc1 = 0.f, acc2 = 0.f;
        #pragma unroll
        for (int s = 0; s < 9; ++s) {
            const int e = s / 3;
            const int c = s - 3 * e;
            float tn   = fmaf(xv[c], 0.125f, qe[e]);
            float segf = fminf(fmaxf(floorf(tn), 0.0f), 63.0f);
            float xl   = fmaf(tn - segf, 2.0f, -1.0f);
            const unsigned int* rp = lw + (((int)segf) << 3) + (s << 9);
            uint4        A  = *(const uint4*)rp;   // ds_read_b128, imm offset s*2048
            unsigned int Bv = rp[4];               // ds_read_b32,  imm offset s*2048+16
            float2 k0 = __half22float2(u2h2(A.x));  // c0_0, c0_1
            float2 k1 = __half22float2(u2h2(A.y));  // c1_0, c1_1
            float2 k2 = __half22float2(u2h2(A.z));  // c2_0, c2_1
            float2 k3 = __half22float2(u2h2(A.w));  // c0_2, c1_2
            float  c22 = __half2float(__low2half(u2h2(Bv)));
            acc0 += fmaf(fmaf(k2.x, xl, k1.x), xl, k0.x);
            acc1 += fmaf(fmaf(k2.y, xl, k1.y), xl, k0.y);
            acc2 += fmaf(fmaf(c22,  xl, k3.y), xl, k3.x);
        }

        float* op = out + ((b * 3) << 18) + p;
        op[0]       = acc0;
        op[1 << 18] = acc1;
        op[2 << 18] = acc2;
    }
}

extern "C" void kernel_launch(void* const* d_in, const int* in_sizes, int n_in,
                              void* d_out, int out_size, void* d_ws, size_t ws_size,
                              hipStream_t stream) {
    const float* x  = (const float*)d_in[0]; // [8,3,512,512]
    const float* Wt = (const float*)d_in[1]; // [4,3,3,129]
    float* out = (float*)d_out;              // [8,3,512,512]

    hipLaunchKernelGGL(stripe_all, dim3(NBLK), dim3(256), 0, stream, x, Wt, out);
}

// Round 2
// 84.884 us; speedup vs baseline: 1.0079x; 1.0013x over previous
//
#include <hip/hip_runtime.h>
#include <hip/hip_fp16.h>
#include <math.h>

// StripePolynomial2d, round 8: v_fma_mix_f32 inner loop.
// R7 post-mortem: occupancy/register theory falsified (2x occupancy change +
// fused phases = 0 delta). Kernel is pipe-bound (LDS ~8.5us, VALU ~7us) or
// overhead-floored. This round cuts inner-loop VALU ~35% by replacing
// (v_cvt_f32_f16 x9 + v_fma x6 + v_add x3) per s with
// (v_fma_mix_f32 x6 + v_add x3): the f16->f32 convert happens inside the
// fma_mix, exactly, so numerics are BIT-IDENTICAL (absmax must stay 0.015625).
// Everything else (table layout, LDS reads, grid 1024x8 tiles, prefetch)
// unchanged from R7 -- single-variable experiment.
// If dur_us doesn't move: kernel is LDS/overhead-floored -> roofline.

#define NREC 576              // 9 ec * 64 seg
#define NTILE 8192            // 8 imgs * 1024 tiles
#define NBLK 1024

__device__ __forceinline__ __half2 u2h2(unsigned int u) {
    __half2 h; __builtin_memcpy(&h, &u, 4); return h;
}
__device__ __forceinline__ unsigned int h22u(__half2 h) {
    unsigned int u; __builtin_memcpy(&u, &h, 4); return u;
}

// D.f32 = cvt(f16) * f32 + cvt(f16)  -- exact cvt, f32 fma.
// suffix letters: operand 0 and 2 half-select (L=lo, H=hi); operand 1 is f32 xl.
#define FMAMIX_T_LL(d, a, xl, b) \
    asm("v_fma_mix_f32 %0, %1, %2, %3 op_sel_hi:[1,0,1]" \
        : "=v"(d) : "v"(a), "v"(xl), "v"(b))
#define FMAMIX_T_HH(d, a, xl, b) \
    asm("v_fma_mix_f32 %0, %1, %2, %3 op_sel:[1,0,1] op_sel_hi:[1,0,1]" \
        : "=v"(d) : "v"(a), "v"(xl), "v"(b))
#define FMAMIX_T_LH(d, a, xl, b) \
    asm("v_fma_mix_f32 %0, %1, %2, %3 op_sel:[0,0,1] op_sel_hi:[1,0,1]" \
        : "=v"(d) : "v"(a), "v"(xl), "v"(b))
// D.f32 = t.f32 * xl.f32 + cvt(f16 lo)
#define FMAMIX_U_L(d, t, xl, b) \
    asm("v_fma_mix_f32 %0, %1, %2, %3 op_sel_hi:[0,0,1]" \
        : "=v"(d) : "v"(t), "v"(xl), "v"(b))
// D.f32 = t.f32 * xl.f32 + cvt(f16 hi)
#define FMAMIX_U_H(d, t, xl, b) \
    asm("v_fma_mix_f32 %0, %1, %2, %3 op_sel:[0,0,1] op_sel_hi:[0,0,1]" \
        : "=v"(d) : "v"(t), "v"(xl), "v"(b))

__device__ __forceinline__ void coeff_compute(const float* __restrict__ Wt, int r,
                                              unsigned int rec[8]) {
    int ec  = r >> 6;
    int seg = r & 63;
    int e   = ec / 3;
    int c   = ec - e * 3;
    int nb  = 2 * seg;
    float c0[3], c1[3], c2[3];
    #pragma unroll
    for (int o = 0; o < 3; ++o) {
        float w0, w1, w2;
        if (e == 0) {
            const float* p0 = Wt + ((0 * 3 + o) * 3 + c) * 129 + nb;
            const float* p1 = Wt + ((1 * 3 + o) * 3 + c) * 129 + nb;
            w0 = p0[0] + p1[0]; w1 = p0[1] + p1[1]; w2 = p0[2] + p1[2];
        } else {
            const float* p = Wt + (((e + 1) * 3 + o) * 3 + c) * 129 + nb;
            w0 = p[0]; w1 = p[1]; w2 = p[2];
        }
        c0[o] = 0.25f  * w1;
        c1[o] = 0.125f * (w2 - w0);
        c2[o] = 0.125f * (w0 + w2) - 0.25f * w1;
    }
    rec[0] = h22u(__floats2half2_rn(c0[0], c0[1]));
    rec[1] = h22u(__floats2half2_rn(c1[0], c1[1]));
    rec[2] = h22u(__floats2half2_rn(c2[0], c2[1]));
    rec[3] = h22u(__floats2half2_rn(c0[2], c1[2]));
    rec[4] = h22u(__floats2half2_rn(c2[2], 0.0f));
    rec[5] = 0u; rec[6] = 0u; rec[7] = 0u;
}

__global__ __launch_bounds__(256, 4) void stripe_all(
    const float* __restrict__ x, const float* __restrict__ Wt,
    float* __restrict__ out)
{
    __shared__ uint4 lw4[NREC * 2];   // 18432 B
    const unsigned int* lw = (const unsigned int*)lw4;
    const int tid = threadIdx.x;

    // ---- prefetch first tile's x while the table is being built ----
    const int t0 = blockIdx.x;
    float pf[3];
    {
        const int b  = t0 >> 10;
        const int p  = ((t0 & 1023) << 8) + tid;
        const int xb = ((b * 3) << 18) + p;
        pf[0] = x[xb];
        pf[1] = x[xb + (1 << 18)];
        pf[2] = x[xb + (2 << 18)];
    }

    // ---- build coeff table once per block ----
    for (int r = tid; r < NREC; r += 256) {
        unsigned int rec[8];
        coeff_compute(Wt, r, rec);
        lw4[2 * r]     = make_uint4(rec[0], rec[1], rec[2], rec[3]);
        lw4[2 * r + 1] = make_uint4(rec[4], rec[5], rec[6], rec[7]);
    }
    __syncthreads();

    // q_e = pos_e/8 + 32, f32 from compile-time f64 constants.
    constexpr double RATIO = 512.0 / 513.0;
    constexpr double CX = 0x1.6a09e667f3bcdp-1;  // cos(f64 pi/4)
    constexpr double SY = 0x1.6a09e667f3bccp-1;  // sin(f64 pi/4), 1 ulp lower
    constexpr double S0 = RATIO * 64.0 / 511.0;
    constexpr double R2MAX = CX * 511.0 + SY * 511.0;
    constexpr double S2 = RATIO * 64.0 / R2MAX;
    constexpr double MN3 = -(SY * 511.0);
    constexpr double MX3 = CX * 511.0;
    constexpr double S3 = RATIO * 64.0 / (MX3 - MN3);

    for (int t = t0; t < NTILE; t += NBLK) {
        const int b = t >> 10;
        const int p = ((t & 1023) << 8) + tid;
        const int w = p >> 9;
        const int h = p & 511;

        // current tile's x (prefetched), then prefetch the next tile's
        float xv[3] = { pf[0], pf[1], pf[2] };
        const int tn_ = t + NBLK;
        if (tn_ < NTILE) {
            const int b2  = tn_ >> 10;
            const int p2  = ((tn_ & 1023) << 8) + tid;
            const int xb2 = ((b2 * 3) << 18) + p2;
            pf[0] = x[xb2];
            pf[1] = x[xb2 + (1 << 18)];
            pf[2] = x[xb2 + (2 << 18)];
        }

        const float wf = (float)w, hf = (float)h;
        float qe[3];
        qe[0] = wf * (float)S0;
        qe[1] = fmaf(hf, (float)(SY * S2), wf * (float)(CX * S2));
        qe[2] = fmaf(hf, (float)(-(SY * S3)),
                     fmaf(wf, (float)(CX * S3), (float)(-MN3 * S3)));

        // ---- fused per-s: seg/xl -> 2 LDS reads -> fma_mix Horner ----
        float acc0 = 0.f, acc1 = 0.f, acc2 = 0.f;
        #pragma unroll
        for (int s = 0; s < 9; ++s) {
            const int e = s / 3;
            const int c = s - 3 * e;
            float tn   = fmaf(xv[c], 0.125f, qe[e]);
            float segf = fminf(fmaxf(floorf(tn), 0.0f), 63.0f);  // -> v_med3_f32
            float xl   = fmaf(tn - segf, 2.0f, -1.0f);
            const unsigned int* rp = lw + (((int)segf) << 3) + (s << 9);
            uint4        A  = *(const uint4*)rp;   // ds_read_b128, imm offset s*2048
            unsigned int Bv = rp[4];               // ds_read_b32,  imm offset s*2048+16
            // A.x = (c0_0,c0_1) A.y = (c1_0,c1_1) A.z = (c2_0,c2_1)
            // A.w = (c0_2,c1_2) Bv.lo = c2_2
            float t0f, t1f, t2f, u0, u1, u2;
            FMAMIX_T_LL(t0f, A.z, xl, A.y);   // c2_0*xl + c1_0
            FMAMIX_T_HH(t1f, A.z, xl, A.y);   // c2_1*xl + c1_1
            FMAMIX_T_LH(t2f, Bv,  xl, A.w);   // c2_2*xl + c1_2
            FMAMIX_U_L(u0, t0f, xl, A.x);     // t0*xl + c0_0
            FMAMIX_U_H(u1, t1f, xl, A.x);     // t1*xl + c0_1
            FMAMIX_U_L(u2, t2f, xl, A.w);     // t2*xl + c0_2
            acc0 += u0;
            acc1 += u1;
            acc2 += u2;
        }

        float* op = out + ((b * 3) << 18) + p;
        op[0]       = acc0;
        op[1 << 18] = acc1;
        op[2 << 18] = acc2;
    }
}

extern "C" void kernel_launch(void* const* d_in, const int* in_sizes, int n_in,
                              void* d_out, int out_size, void* d_ws, size_t ws_size,
                              hipStream_t stream) {
    const float* x  = (const float*)d_in[0]; // [8,3,512,512]
    const float* Wt = (const float*)d_in[1]; // [4,3,3,129]
    float* out = (float*)d_out;              // [8,3,512,512]

    hipLaunchKernelGGL(stripe_all, dim3(NBLK), dim3(256), 0, stream, x, Wt, out);
}